// Round 2
// baseline (1280.792 us; speedup 1.0000x reference)
//
#include <hip/hip_runtime.h>

#define SEQ 4096
#define NBATCH 256

__device__ __forceinline__ float sqf(float v) { return v * v; }

// fast exp2 / rcp (v_exp_f32 / v_rcp_f32, ~1 ulp)
__device__ __forceinline__ float fexp2(float v) { return __builtin_amdgcn_exp2f(v); }
__device__ __forceinline__ float frcp(float v)  { return __builtin_amdgcn_rcpf(v); }

// ---------------------------------------------------------------------------
// Kernel 1: conv branches + per-batch max + (conv+max)^2 + analytic scatter
// Builds lin (B, S, 24) = concat(branch4..branch8, inp_r) and xsum (B, S).
// One block per batch row.
// ---------------------------------------------------------------------------
__global__ __launch_bounds__(256) void prep_kernel(
    const float* __restrict__ x,
    const float* __restrict__ w4p, const float* __restrict__ w5p,
    const float* __restrict__ w6p, const float* __restrict__ w7p,
    const float* __restrict__ w8p,
    float* __restrict__ lin,
    float* __restrict__ xsum)
{
    const int b   = blockIdx.x;
    const int tid = threadIdx.x;
    const float* __restrict__ xr = x + (size_t)b * (4 * SEQ);

    float W4[4], W5[5], W6[6], W7[7], W8[8];
#pragma unroll
    for (int k = 0; k < 4; ++k) W4[k] = w4p[k];
#pragma unroll
    for (int k = 0; k < 5; ++k) W5[k] = w5p[k];
#pragma unroll
    for (int k = 0; k < 6; ++k) W6[k] = w6p[k];
#pragma unroll
    for (int k = 0; k < 7; ++k) W7[k] = w7p[k];
#pragma unroll
    for (int k = 0; k < 8; ++k) W8[k] = w8p[k];

    // ---- Phase A: per-filter max over all conv positions ----
    // conv_fs[i] valid for i < L_fs; L4 = 4096, L5..L8 = 4095.
    float m4 = -3.4e38f, m5 = -3.4e38f, m6 = -3.4e38f, m7 = -3.4e38f, m8 = -3.4e38f;
    for (int i = tid; i < SEQ; i += 256) {
        const float4 t0 = *reinterpret_cast<const float4*>(xr + 4 * i);
        const float xa0 = t0.x, xa1 = t0.y, xa2 = t0.z, xa3 = t0.w;
        const float c4 = xa0 * W4[0] + xa1 * W4[1] + xa2 * W4[2] + xa3 * W4[3];
        m4 = fmaxf(m4, c4);
        if (i < SEQ - 1) {
            const float4 t1 = *reinterpret_cast<const float4*>(xr + 4 * i + 4);
            const float xa4 = t1.x, xa5 = t1.y, xa6 = t1.z, xa7 = t1.w;
            const float c5 = xa0*W5[0]+xa1*W5[1]+xa2*W5[2]+xa3*W5[3]+xa4*W5[4];
            const float c6 = xa0*W6[0]+xa1*W6[1]+xa2*W6[2]+xa3*W6[3]+xa4*W6[4]+xa5*W6[5];
            const float c7 = xa0*W7[0]+xa1*W7[1]+xa2*W7[2]+xa3*W7[3]+xa4*W7[4]+xa5*W7[5]+xa6*W7[6];
            const float c8 = xa0*W8[0]+xa1*W8[1]+xa2*W8[2]+xa3*W8[3]+xa4*W8[4]+xa5*W8[5]+xa6*W8[6]+xa7*W8[7];
            m5 = fmaxf(m5, c5); m6 = fmaxf(m6, c6);
            m7 = fmaxf(m7, c7); m8 = fmaxf(m8, c8);
        }
    }
#pragma unroll
    for (int off = 32; off; off >>= 1) {
        m4 = fmaxf(m4, __shfl_down(m4, off));
        m5 = fmaxf(m5, __shfl_down(m5, off));
        m6 = fmaxf(m6, __shfl_down(m6, off));
        m7 = fmaxf(m7, __shfl_down(m7, off));
        m8 = fmaxf(m8, __shfl_down(m8, off));
    }
    __shared__ float wr[4][5];
    __shared__ float MM[5];
    if ((tid & 63) == 0) {
        const int w = tid >> 6;
        wr[w][0] = m4; wr[w][1] = m5; wr[w][2] = m6; wr[w][3] = m7; wr[w][4] = m8;
    }
    __syncthreads();
    if (tid < 5)
        MM[tid] = fmaxf(fmaxf(wr[0][tid], wr[1][tid]), fmaxf(wr[2][tid], wr[3][tid]));
    __syncthreads();
    const float M4 = MM[0], M5 = MM[1], M6 = MM[2], M7 = MM[3], M8 = MM[4];

    // ---- Phase B: winner-takes-all + scatter, built analytically per s ----
    // branch_fs[b, 4s+c] = sum of v_fs[i] over i with 0 <= 4s+c-4i < fs:
    //   i = s   (j=c, always < fs)            [valid if s < L_fs]
    //   i = s-1 (j=c+4, needs c+4 < fs)       [valid if s >= 1]
    for (int s = tid; s < SEQ; s += 256) {
        float xw[12];  // x[4s-4 .. 4s+7]
        if (s > 0) {
            const float4 t = *reinterpret_cast<const float4*>(xr + 4 * s - 4);
            xw[0] = t.x; xw[1] = t.y; xw[2] = t.z; xw[3] = t.w;
        } else { xw[0] = xw[1] = xw[2] = xw[3] = 0.f; }
        {
            const float4 t = *reinterpret_cast<const float4*>(xr + 4 * s);
            xw[4] = t.x; xw[5] = t.y; xw[6] = t.z; xw[7] = t.w;
        }
        if (s < SEQ - 1) {
            const float4 t = *reinterpret_cast<const float4*>(xr + 4 * s + 4);
            xw[8] = t.x; xw[9] = t.y; xw[10] = t.z; xw[11] = t.w;
        } else { xw[8] = xw[9] = xw[10] = xw[11] = 0.f; }

        float c4s = 0.f, c5s = 0.f, c6s = 0.f, c7s = 0.f, c8s = 0.f;
        float c5p = 0.f, c6p = 0.f, c7p = 0.f, c8p = 0.f;
#pragma unroll
        for (int t = 0; t < 4; ++t) c4s += xw[4 + t] * W4[t];
#pragma unroll
        for (int t = 0; t < 5; ++t) { c5s += xw[4 + t] * W5[t]; c5p += xw[t] * W5[t]; }
#pragma unroll
        for (int t = 0; t < 6; ++t) { c6s += xw[4 + t] * W6[t]; c6p += xw[t] * W6[t]; }
#pragma unroll
        for (int t = 0; t < 7; ++t) { c7s += xw[4 + t] * W7[t]; c7p += xw[t] * W7[t]; }
#pragma unroll
        for (int t = 0; t < 8; ++t) { c8s += xw[4 + t] * W8[t]; c8p += xw[t] * W8[t]; }

        const bool oks = (s < SEQ - 1);   // i = s valid for fs>=5 (L=4095)
        const bool okp = (s > 0);         // i = s-1 exists
        const float v4s = sqf(c4s + M4);
        const float v5s = oks ? sqf(c5s + M5) : 0.f;
        const float v6s = oks ? sqf(c6s + M6) : 0.f;
        const float v7s = oks ? sqf(c7s + M7) : 0.f;
        const float v8s = oks ? sqf(c8s + M8) : 0.f;
        const float v5p = okp ? sqf(c5p + M5) : 0.f;
        const float v6p = okp ? sqf(c6p + M6) : 0.f;
        const float v7p = okp ? sqf(c7p + M7) : 0.f;
        const float v8p = okp ? sqf(c8p + M8) : 0.f;

        float4* op = reinterpret_cast<float4*>(lin + ((size_t)b * SEQ + s) * 24);
        op[0] = make_float4(v4s, v4s, v4s, v4s);
        op[1] = make_float4(v5s + v5p, v5s, v5s, v5s);
        op[2] = make_float4(v6s + v6p, v6s + v6p, v6s, v6s);
        op[3] = make_float4(v7s + v7p, v7s + v7p, v7s + v7p, v7s);
        op[4] = make_float4(v8s + v8p, v8s + v8p, v8s + v8p, v8s + v8p);
        op[5] = make_float4(xw[4], xw[5], xw[6], xw[7]);
        xsum[(size_t)b * SEQ + s] = (xw[4] + xw[5]) + (xw[6] + xw[7]);
    }
}

// ---------------------------------------------------------------------------
// Kernel 2: bidirectional LSTM, one wave per (direction, batch) chain.
// Lane layout: lane = 4*j + t, j = hidden unit (0..9), t = gate {i,f,g,o}.
// Gate preactivation per lane; h broadcast via v_readlane from quad leaders;
// i/f/g/o exchange via DPP quad_perm; c/h updated redundantly in all 4 quad
// lanes. Running accumulator accS = sum_s xsum[b,s]*h_own (each unit counted
// 4x -> /4 at the end). Epilogue: P[d*256+b] = sum_s xsum * sum_j h_j.
// ---------------------------------------------------------------------------
__global__ __launch_bounds__(64) void lstm_kernel(
    const float* __restrict__ lin,
    const float* __restrict__ xsum,
    const float* __restrict__ Wih_f, const float* __restrict__ Whh_f,
    const float* __restrict__ bih_f, const float* __restrict__ bhh_f,
    const float* __restrict__ Wih_r, const float* __restrict__ Whh_r,
    const float* __restrict__ bih_r, const float* __restrict__ bhh_r,
    float* __restrict__ P)
{
    const int bx   = blockIdx.x;
    const int d    = bx >> 8;      // 0 = forward, 1 = reverse
    const int b    = bx & 255;
    const int lane = threadIdx.x;
    const int j    = lane >> 2;
    const int t    = lane & 3;
    int r = t * 10 + j;            // torch gate-row: i=0..9, f=10..19, g=20..29, o=30..39
    if (lane >= 40) r = 0;         // clamp idle lanes, avoid OOB weight reads

    const float* __restrict__ Wih = d ? Wih_r : Wih_f;
    const float* __restrict__ Whh = d ? Whh_r : Whh_f;
    const float* __restrict__ bih = d ? bih_r : bih_f;
    const float* __restrict__ bhh = d ? bhh_r : bhh_f;

    float wih[24], whh[10];
#pragma unroll
    for (int k = 0; k < 24; ++k) wih[k] = Wih[r * 24 + k];
#pragma unroll
    for (int k = 0; k < 10; ++k) whh[k] = Whh[r * 10 + k];
    const float bias = bih[r] + bhh[r];

    // fused activation: sigmoid(x) = rcp(1+2^(-x*log2e))
    //                   tanh(x)    = 2*rcp(1+2^(-2x*log2e)) - 1   (g-gate lanes)
    const float LOG2E = 1.4426950408889634f;
    const float mpre  = (t == 2) ? (-2.f * LOG2E) : (-LOG2E);
    const float mpost = (t == 2) ? 2.f : 1.f;
    const float apost = (t == 2) ? -1.f : 0.f;

    const float* __restrict__ rowbase = lin + (size_t)b * SEQ * 24;
    const float* __restrict__ xsrow   = xsum + (size_t)b * SEQ;

    const int s0 = d ? (SEQ - 1) : 0;
    const int ds = d ? -1 : 1;

    float h = 0.f, c = 0.f, accS = 0.f;
    float bufA[25], bufB[25];

    auto loadbuf = [&](float (&buf)[25], int s) {
        const float* __restrict__ p = rowbase + (size_t)s * 24;
#pragma unroll
        for (int k = 0; k < 24; ++k) buf[k] = p[k];
        buf[24] = xsrow[s];
    };

    auto step = [&](const float (&buf)[25]) {
        // input-side preactivation (off the h->h critical path; 4 partial accs)
        float a0 = bias, a1 = 0.f, a2 = 0.f, a3 = 0.f;
#pragma unroll
        for (int k = 0; k < 24; k += 4) {
            a0 = fmaf(buf[k + 0], wih[k + 0], a0);
            a1 = fmaf(buf[k + 1], wih[k + 1], a1);
            a2 = fmaf(buf[k + 2], wih[k + 2], a2);
            a3 = fmaf(buf[k + 3], wih[k + 3], a3);
        }
        float acc = (a0 + a1) + (a2 + a3);
        // recurrent part: broadcast h_j from quad leaders via readlane
        const int hbits = __float_as_int(h);
        float b0 = 0.f, b1 = 0.f;
#pragma unroll
        for (int k = 0; k < 10; k += 2) {
            const float h0 = __int_as_float(__builtin_amdgcn_readlane(hbits, 4 * k));
            const float h1 = __int_as_float(__builtin_amdgcn_readlane(hbits, 4 * (k + 1)));
            b0 = fmaf(h0, whh[k + 0], b0);
            b1 = fmaf(h1, whh[k + 1], b1);
        }
        acc += b0 + b1;
        // activation (sigmoid or tanh via lane-constant coefficients)
        const float u  = fexp2(acc * mpre);
        const float rr = frcp(1.f + u);
        const float a  = fmaf(rr, mpost, apost);
        // quad exchange: every lane grabs i,f,g,o of its unit (DPP quad_perm)
        const int ab = __float_as_int(a);
        const float iv = __int_as_float(__builtin_amdgcn_update_dpp(ab, ab, 0x00, 0xF, 0xF, false));
        const float fv = __int_as_float(__builtin_amdgcn_update_dpp(ab, ab, 0x55, 0xF, 0xF, false));
        const float gv = __int_as_float(__builtin_amdgcn_update_dpp(ab, ab, 0xAA, 0xF, 0xF, false));
        const float ov = __int_as_float(__builtin_amdgcn_update_dpp(ab, ab, 0xFF, 0xF, 0xF, false));
        // cell/hidden update (redundant across the quad)
        c = fmaf(fv, c, iv * gv);
        const float u2 = fexp2(c * (-2.f * LOG2E));
        const float r2 = frcp(1.f + u2);
        const float th = fmaf(2.f, r2, -1.f);
        h = ov * th;
        // epilogue accumulation: sum_s xsum[b,s] * h (unit counted 4x)
        accS = fmaf(buf[24], h, accS);
    };

    loadbuf(bufA, s0);
    int s = s0;
    for (int it = 0; it < SEQ; it += 2) {
        loadbuf(bufB, s + ds);                    // prefetch step it+1
        step(bufA);
        s += ds;
        if (it + 2 < SEQ) loadbuf(bufA, s + ds);  // prefetch step it+2
        step(bufB);
        s += ds;
    }

    float v = (lane < 40) ? accS * 0.25f : 0.f;
#pragma unroll
    for (int off = 32; off; off >>= 1) v += __shfl_down(v, off);
    if (lane == 0) P[(d << 8) + b] = v;
}

// ---------------------------------------------------------------------------
// Kernel 3: out[b] = sigmoid(P_f[b] + P_r[b])
// ---------------------------------------------------------------------------
__global__ __launch_bounds__(256) void final_kernel(const float* __restrict__ P,
                                                    float* __restrict__ out)
{
    const int b = threadIdx.x;
    const float v = P[b] + P[NBATCH + b];
    const float LOG2E = 1.4426950408889634f;
    out[b] = frcp(1.f + fexp2(-v * LOG2E));
}

extern "C" void kernel_launch(void* const* d_in, const int* in_sizes, int n_in,
                              void* d_out, int out_size, void* d_ws, size_t ws_size,
                              hipStream_t stream)
{
    const float* x     = (const float*)d_in[0];
    const float* w4    = (const float*)d_in[1];
    const float* w5    = (const float*)d_in[2];
    const float* w6    = (const float*)d_in[3];
    const float* w7    = (const float*)d_in[4];
    const float* w8    = (const float*)d_in[5];
    const float* Wih_f = (const float*)d_in[6];
    const float* Whh_f = (const float*)d_in[7];
    const float* bih_f = (const float*)d_in[8];
    const float* bhh_f = (const float*)d_in[9];
    const float* Wih_r = (const float*)d_in[10];
    const float* Whh_r = (const float*)d_in[11];
    const float* bih_r = (const float*)d_in[12];
    const float* bhh_r = (const float*)d_in[13];

    // workspace layout (fp32): lin (256*4096*24) | xsum (256*4096) | P (512)
    float* lin = (float*)d_ws;
    float* xs  = lin + (size_t)NBATCH * SEQ * 24;
    float* P   = xs + (size_t)NBATCH * SEQ;

    prep_kernel<<<NBATCH, 256, 0, stream>>>(x, w4, w5, w6, w7, w8, lin, xs);
    lstm_kernel<<<2 * NBATCH, 64, 0, stream>>>(lin, xs, Wih_f, Whh_f, bih_f, bhh_f,
                                               Wih_r, Whh_r, bih_r, bhh_r, P);
    final_kernel<<<1, NBATCH, 0, stream>>>(P, (float*)d_out);
}

// Round 4
// 560.217 us; speedup vs baseline: 2.2862x; 2.2862x over previous
//
#include <hip/hip_runtime.h>

#define SEQ 4096
#define NBATCH 256

__device__ __forceinline__ float sqf(float v) { return v * v; }
__device__ __forceinline__ float fexp2(float v) { return __builtin_amdgcn_exp2f(v); }
__device__ __forceinline__ float frcp(float v)  { return __builtin_amdgcn_rcpf(v); }

#define L2E 1.4426950408889634f

// ---------------------------------------------------------------------------
// Kernel 1 (proven in round 2): conv branches + per-batch max + (conv+max)^2
// + analytic scatter. Builds lin (B, S, 24). One block per batch row.
// ---------------------------------------------------------------------------
__global__ __launch_bounds__(256) void prep_kernel(
    const float* __restrict__ x,
    const float* __restrict__ w4p, const float* __restrict__ w5p,
    const float* __restrict__ w6p, const float* __restrict__ w7p,
    const float* __restrict__ w8p,
    float* __restrict__ lin)
{
    const int b   = blockIdx.x;
    const int tid = threadIdx.x;
    const float* __restrict__ xr = x + (size_t)b * (4 * SEQ);

    float W4[4], W5[5], W6[6], W7[7], W8[8];
#pragma unroll
    for (int k = 0; k < 4; ++k) W4[k] = w4p[k];
#pragma unroll
    for (int k = 0; k < 5; ++k) W5[k] = w5p[k];
#pragma unroll
    for (int k = 0; k < 6; ++k) W6[k] = w6p[k];
#pragma unroll
    for (int k = 0; k < 7; ++k) W7[k] = w7p[k];
#pragma unroll
    for (int k = 0; k < 8; ++k) W8[k] = w8p[k];

    // ---- Phase A: per-filter max over all conv positions ----
    float m4 = -3.4e38f, m5 = -3.4e38f, m6 = -3.4e38f, m7 = -3.4e38f, m8 = -3.4e38f;
    for (int i = tid; i < SEQ; i += 256) {
        const float4 t0 = *reinterpret_cast<const float4*>(xr + 4 * i);
        const float xa0 = t0.x, xa1 = t0.y, xa2 = t0.z, xa3 = t0.w;
        const float c4 = xa0 * W4[0] + xa1 * W4[1] + xa2 * W4[2] + xa3 * W4[3];
        m4 = fmaxf(m4, c4);
        if (i < SEQ - 1) {
            const float4 t1 = *reinterpret_cast<const float4*>(xr + 4 * i + 4);
            const float xa4 = t1.x, xa5 = t1.y, xa6 = t1.z, xa7 = t1.w;
            const float c5 = xa0*W5[0]+xa1*W5[1]+xa2*W5[2]+xa3*W5[3]+xa4*W5[4];
            const float c6 = xa0*W6[0]+xa1*W6[1]+xa2*W6[2]+xa3*W6[3]+xa4*W6[4]+xa5*W6[5];
            const float c7 = xa0*W7[0]+xa1*W7[1]+xa2*W7[2]+xa3*W7[3]+xa4*W7[4]+xa5*W7[5]+xa6*W7[6];
            const float c8 = xa0*W8[0]+xa1*W8[1]+xa2*W8[2]+xa3*W8[3]+xa4*W8[4]+xa5*W8[5]+xa6*W8[6]+xa7*W8[7];
            m5 = fmaxf(m5, c5); m6 = fmaxf(m6, c6);
            m7 = fmaxf(m7, c7); m8 = fmaxf(m8, c8);
        }
    }
#pragma unroll
    for (int off = 32; off; off >>= 1) {
        m4 = fmaxf(m4, __shfl_down(m4, off));
        m5 = fmaxf(m5, __shfl_down(m5, off));
        m6 = fmaxf(m6, __shfl_down(m6, off));
        m7 = fmaxf(m7, __shfl_down(m7, off));
        m8 = fmaxf(m8, __shfl_down(m8, off));
    }
    __shared__ float wr[4][5];
    __shared__ float MM[5];
    if ((tid & 63) == 0) {
        const int w = tid >> 6;
        wr[w][0] = m4; wr[w][1] = m5; wr[w][2] = m6; wr[w][3] = m7; wr[w][4] = m8;
    }
    __syncthreads();
    if (tid < 5)
        MM[tid] = fmaxf(fmaxf(wr[0][tid], wr[1][tid]), fmaxf(wr[2][tid], wr[3][tid]));
    __syncthreads();
    const float M4 = MM[0], M5 = MM[1], M6 = MM[2], M7 = MM[3], M8 = MM[4];

    // ---- Phase B: winner-takes-all + analytic scatter ----
    for (int s = tid; s < SEQ; s += 256) {
        float xw[12];
        if (s > 0) {
            const float4 t = *reinterpret_cast<const float4*>(xr + 4 * s - 4);
            xw[0] = t.x; xw[1] = t.y; xw[2] = t.z; xw[3] = t.w;
        } else { xw[0] = xw[1] = xw[2] = xw[3] = 0.f; }
        {
            const float4 t = *reinterpret_cast<const float4*>(xr + 4 * s);
            xw[4] = t.x; xw[5] = t.y; xw[6] = t.z; xw[7] = t.w;
        }
        if (s < SEQ - 1) {
            const float4 t = *reinterpret_cast<const float4*>(xr + 4 * s + 4);
            xw[8] = t.x; xw[9] = t.y; xw[10] = t.z; xw[11] = t.w;
        } else { xw[8] = xw[9] = xw[10] = xw[11] = 0.f; }

        float c4s = 0.f, c5s = 0.f, c6s = 0.f, c7s = 0.f, c8s = 0.f;
        float c5p = 0.f, c6p = 0.f, c7p = 0.f, c8p = 0.f;
#pragma unroll
        for (int t = 0; t < 4; ++t) c4s += xw[4 + t] * W4[t];
#pragma unroll
        for (int t = 0; t < 5; ++t) { c5s += xw[4 + t] * W5[t]; c5p += xw[t] * W5[t]; }
#pragma unroll
        for (int t = 0; t < 6; ++t) { c6s += xw[4 + t] * W6[t]; c6p += xw[t] * W6[t]; }
#pragma unroll
        for (int t = 0; t < 7; ++t) { c7s += xw[4 + t] * W7[t]; c7p += xw[t] * W7[t]; }
#pragma unroll
        for (int t = 0; t < 8; ++t) { c8s += xw[4 + t] * W8[t]; c8p += xw[t] * W8[t]; }

        const bool oks = (s < SEQ - 1);
        const bool okp = (s > 0);
        const float v4s = sqf(c4s + M4);
        const float v5s = oks ? sqf(c5s + M5) : 0.f;
        const float v6s = oks ? sqf(c6s + M6) : 0.f;
        const float v7s = oks ? sqf(c7s + M7) : 0.f;
        const float v8s = oks ? sqf(c8s + M8) : 0.f;
        const float v5p = okp ? sqf(c5p + M5) : 0.f;
        const float v6p = okp ? sqf(c6p + M6) : 0.f;
        const float v7p = okp ? sqf(c7p + M7) : 0.f;
        const float v8p = okp ? sqf(c8p + M8) : 0.f;

        float4* op = reinterpret_cast<float4*>(lin + ((size_t)b * SEQ + s) * 24);
        op[0] = make_float4(v4s, v4s, v4s, v4s);
        op[1] = make_float4(v5s + v5p, v5s, v5s, v5s);
        op[2] = make_float4(v6s + v6p, v6s + v6p, v6s, v6s);
        op[3] = make_float4(v7s + v7p, v7s + v7p, v7s + v7p, v7s);
        op[4] = make_float4(v8s + v8p, v8s + v8p, v8s + v8p, v8s + v8p);
        op[5] = make_float4(xw[4], xw[5], xw[6], xw[7]);
    }
}

// ---------------------------------------------------------------------------
// Kernel 2: bidirectional LSTM — producer/consumer, one block (128 thr =
// 2 waves) per (direction, batch) chain; 512 blocks = 1024 waves.
//  wave 1 (producer): per 64-step chunk, one step per lane; reads lin row
//    (6x float4, coalesced), computes all 40 gate preactivations pre-scaled
//    by mpre_r, plus xsum; writes LDS ring (stride 41 -> conflict-free).
//  wave 0 (consumer): recurrence. Lane = 4*j + t (j unit, t gate i,f,g,o).
//    Per step: 1 ds_read gp + 1 broadcast xsum; 10 readlane h-broadcasts;
//    folded activation algebra (cs = -2*log2e*c state; whh pre-scaled;
//    post-scales folded into the sigma fma).
// ---------------------------------------------------------------------------
__global__ __launch_bounds__(128) void lstm_kernel(
    const float* __restrict__ lin,
    const float* __restrict__ Wih_f, const float* __restrict__ bih_f,
    const float* __restrict__ bhh_f, const float* __restrict__ Whh_f,
    const float* __restrict__ Wih_r, const float* __restrict__ bih_r,
    const float* __restrict__ bhh_r, const float* __restrict__ Whh_r,
    float* __restrict__ P)
{
    const int cb  = blockIdx.x;          // (d<<8) + b
    const int d   = cb >> 8;
    const int b   = cb & 255;
    const int tid = threadIdx.x;

    __shared__ float gbuf[2][64 * 41];
    __shared__ float xbuf[2][64];

    const float* __restrict__ Wih = d ? Wih_r : Wih_f;
    const float* __restrict__ bi  = d ? bih_r : bih_f;
    const float* __restrict__ bh  = d ? bhh_r : bhh_f;
    const float* __restrict__ Whh = d ? Whh_r : Whh_f;

    // ---- consumer setup (all threads compute it; harmless for wave 1) ----
    const int lane = tid & 63;
    const int j    = lane >> 2;
    const int t    = lane & 3;
    int row = t * 10 + j;
    if (lane >= 40) row = 0;

    const float mpre = (t == 2) ? (-2.f * L2E) : (-L2E);
    float whh[10];
#pragma unroll
    for (int k = 0; k < 10; ++k) whh[k] = Whh[row * 10 + k] * mpre;
    const float mpost = (t == 0) ? (-2.f * L2E) : ((t == 1) ? 1.f : 2.f);
    const float apost = (t == 2) ? -1.f : 0.f;

    // ---- producer lambda: fill chunk cn into ring cn&1 ----
    auto produce = [&](int cn) {
        const int l   = tid & 63;
        const int sp  = cn * 64 + l;
        const int src = d ? (SEQ - 1 - sp) : sp;
        const float* __restrict__ vp = lin + ((size_t)b * SEQ + src) * 24;
        float v[24];
#pragma unroll
        for (int q = 0; q < 6; ++q) {
            const float4 t4 = reinterpret_cast<const float4*>(vp)[q];
            v[4 * q + 0] = t4.x; v[4 * q + 1] = t4.y;
            v[4 * q + 2] = t4.z; v[4 * q + 3] = t4.w;
        }
        const int ring = cn & 1;
        xbuf[ring][l] = (v[20] + v[21]) + (v[22] + v[23]);
        for (int r = 0; r < 40; ++r) {
            float a0 = bi[r] + bh[r], a1 = 0.f, a2 = 0.f, a3 = 0.f;
#pragma unroll
            for (int k = 0; k < 24; k += 4) {
                a0 = fmaf(v[k + 0], Wih[r * 24 + k + 0], a0);
                a1 = fmaf(v[k + 1], Wih[r * 24 + k + 1], a1);
                a2 = fmaf(v[k + 2], Wih[r * 24 + k + 2], a2);
                a3 = fmaf(v[k + 3], Wih[r * 24 + k + 3], a3);
            }
            const float sc = (r >= 20 && r < 30) ? (-2.f * L2E) : (-L2E);
            gbuf[ring][l * 41 + r] = ((a0 + a1) + (a2 + a3)) * sc;
        }
    };

    float cs = 0.f, h = 0.f, accS = 0.f;

    if (tid >= 64) produce(0);
    __syncthreads();

    for (int c = 0; c < 64; ++c) {
        if (tid < 64) {
            const int ring = c & 1;
#pragma unroll 8
            for (int i = 0; i < 64; ++i) {
                const float g  = gbuf[ring][i * 41 + row];
                const float sx = xbuf[ring][i];
                // recurrent matvec: broadcast h_j from quad leaders
                const int hb = __float_as_int(h);
                float a0 = g, a1, a2, a3;
                a0 = fmaf(__int_as_float(__builtin_amdgcn_readlane(hb,  0)), whh[0], a0);
                a1 =      __int_as_float(__builtin_amdgcn_readlane(hb,  4)) * whh[1];
                a2 =      __int_as_float(__builtin_amdgcn_readlane(hb,  8)) * whh[2];
                a3 =      __int_as_float(__builtin_amdgcn_readlane(hb, 12)) * whh[3];
                a0 = fmaf(__int_as_float(__builtin_amdgcn_readlane(hb, 16)), whh[4], a0);
                a1 = fmaf(__int_as_float(__builtin_amdgcn_readlane(hb, 20)), whh[5], a1);
                a2 = fmaf(__int_as_float(__builtin_amdgcn_readlane(hb, 24)), whh[6], a2);
                a3 = fmaf(__int_as_float(__builtin_amdgcn_readlane(hb, 28)), whh[7], a3);
                a0 = fmaf(__int_as_float(__builtin_amdgcn_readlane(hb, 32)), whh[8], a0);
                a1 = fmaf(__int_as_float(__builtin_amdgcn_readlane(hb, 36)), whh[9], a1);
                const float e = (a0 + a2) + (a1 + a3);
                // gate activation: rr = sigma (t!=2) or (tanh+1)/2 (t==2)
                const float u1 = fexp2(e);
                const float rr = frcp(1.f + u1);
                const float a  = fmaf(rr, mpost, apost);
                // quad exchange
                const int ab = __float_as_int(a);
                const float iv  = __int_as_float(__builtin_amdgcn_update_dpp(ab, ab, 0x00, 0xF, 0xF, false));
                const float fv  = __int_as_float(__builtin_amdgcn_update_dpp(ab, ab, 0x55, 0xF, 0xF, false));
                const float gv  = __int_as_float(__builtin_amdgcn_update_dpp(ab, ab, 0xAA, 0xF, 0xF, false));
                const float ov2 = __int_as_float(__builtin_amdgcn_update_dpp(ab, ab, 0xFF, 0xF, 0xF, false));
                // cs = -2log2e * c ;  iv pre-scaled by -2log2e
                cs = fmaf(fv, cs, iv * gv);
                const float movh = -0.5f * ov2;
                const float u2 = fexp2(cs);
                const float r2 = frcp(1.f + u2);
                h = fmaf(ov2, r2, movh);       // = o * tanh(c)
                accS = fmaf(sx, h, accS);
            }
        } else if (c + 1 < 64) {
            produce(c + 1);
        }
        __syncthreads();
    }

    if (tid < 64) {
        float v = (lane < 40) ? accS * 0.25f : 0.f;
#pragma unroll
        for (int off = 32; off; off >>= 1) v += __shfl_down(v, off);
        if (lane == 0) P[cb] = v;
    }
}

// ---------------------------------------------------------------------------
// Kernel 3: out[b] = sigmoid(P_f[b] + P_r[b])
// ---------------------------------------------------------------------------
__global__ __launch_bounds__(256) void final_kernel(const float* __restrict__ P,
                                                    float* __restrict__ out)
{
    const int b = threadIdx.x;
    const float v = P[b] + P[NBATCH + b];
    out[b] = frcp(1.f + fexp2(-v * L2E));
}

extern "C" void kernel_launch(void* const* d_in, const int* in_sizes, int n_in,
                              void* d_out, int out_size, void* d_ws, size_t ws_size,
                              hipStream_t stream)
{
    const float* x     = (const float*)d_in[0];
    const float* w4    = (const float*)d_in[1];
    const float* w5    = (const float*)d_in[2];
    const float* w6    = (const float*)d_in[3];
    const float* w7    = (const float*)d_in[4];
    const float* w8    = (const float*)d_in[5];
    const float* Wih_f = (const float*)d_in[6];
    const float* Whh_f = (const float*)d_in[7];
    const float* bih_f = (const float*)d_in[8];
    const float* bhh_f = (const float*)d_in[9];
    const float* Wih_r = (const float*)d_in[10];
    const float* Whh_r = (const float*)d_in[11];
    const float* bih_r = (const float*)d_in[12];
    const float* bhh_r = (const float*)d_in[13];

    // ws layout (fp32): lin [256][4096][24] | P [512]   (~100.7 MB, proven)
    float* lin = (float*)d_ws;
    float* P   = lin + (size_t)NBATCH * SEQ * 24;

    prep_kernel<<<NBATCH, 256, 0, stream>>>(x, w4, w5, w6, w7, w8, lin);
    lstm_kernel<<<2 * NBATCH, 128, 0, stream>>>(lin,
                                                Wih_f, bih_f, bhh_f, Whh_f,
                                                Wih_r, bih_r, bhh_r, Whh_r, P);
    final_kernel<<<1, NBATCH, 0, stream>>>(P, (float*)d_out);
}